// Round 1
// 8344.286 us; speedup vs baseline: 4.8886x; 4.8886x over previous
//
#include <hip/hip_runtime.h>

#define KK 27
#define NPTS 1000000
#define C 16
#define TOTE (KK * NPTS)        // 27,000,000 kernel-map entries per conv
#define HALF (NPTS / 2)         // output rows per processing half
#define NBLK1 3907              // ceil(NPTS/256) for the scan

typedef unsigned int u32;
typedef unsigned char u8;

__device__ __forceinline__ double elu64(double x) { return x > 0.0 ? x : expm1(x); }

__device__ __forceinline__ void atomAddF64(double* p, double v) {
#if defined(__gfx90a__) || defined(__gfx940__) || defined(__gfx941__) || defined(__gfx942__) || defined(__gfx950__)
    unsafeAtomicAdd(p, v);
#else
    atomicAdd(p, v);
#endif
}

// ---------------- binning: histogram + remember my slot (u8) ----------------
// One device-scope atomic per entry (vs 16 f64 atomics per entry before).
__global__ void __launch_bounds__(256) hist_pos(
    const int* __restrict__ out_map, u32* __restrict__ bins, u8* __restrict__ posb)
{
    const int e = blockIdx.x * 256 + threadIdx.x;
    if (e >= TOTE) return;
    const int j = out_map[e];
    posb[e] = (u8)atomicAdd(&bins[j], 1u);   // bin sizes ~Poisson(27), max ~80 << 255
}

// ---------------- exclusive scan of bins[0..NPTS) (3-kernel textbook) ----------------
__global__ void __launch_bounds__(256) scan_k1(u32* __restrict__ bins, u32* __restrict__ partials)
{
    __shared__ u32 sd[256];
    const int t = threadIdx.x;
    const int i = blockIdx.x * 256 + t;
    const u32 v = (i < NPTS) ? bins[i] : 0u;
    sd[t] = v;
    __syncthreads();
    for (int off = 1; off < 256; off <<= 1) {
        const u32 x = (t >= off) ? sd[t - off] : 0u;
        __syncthreads();
        sd[t] += x;
        __syncthreads();
    }
    if (i < NPTS) bins[i] = sd[t] - v;          // exclusive within block
    if (t == 255) partials[blockIdx.x] = sd[255];
}

__global__ void __launch_bounds__(256) scan_k2(u32* __restrict__ partials)
{
    __shared__ u32 sd[256];
    const int t = threadIdx.x;
    u32 loc[16];
    u32 sum = 0;
#pragma unroll
    for (int u = 0; u < 16; ++u) {
        const int idx = t * 16 + u;
        loc[u] = (idx < NBLK1) ? partials[idx] : 0u;
        sum += loc[u];
    }
    sd[t] = sum;
    __syncthreads();
    for (int off = 1; off < 256; off <<= 1) {
        const u32 x = (t >= off) ? sd[t - off] : 0u;
        __syncthreads();
        sd[t] += x;
        __syncthreads();
    }
    u32 run = sd[t] - sum;                      // exclusive chunk base
#pragma unroll
    for (int u = 0; u < 16; ++u) {
        const int idx = t * 16 + u;
        if (idx < NBLK1) partials[idx] = run;
        run += loc[u];
    }
}

__global__ void __launch_bounds__(256) scan_k3(u32* __restrict__ bins, const u32* __restrict__ partials)
{
    const int i = blockIdx.x * 256 + threadIdx.x;
    if (i < NPTS) bins[i] += partials[blockIdx.x];
    if (i == 0) bins[NPTS] = (u32)TOTE;
}

// ---------------- fill entries for output rows [rlo, rhi) — NO atomics ----------------
// entry = (k << 20) | in_row   (k < 27 -> 5 bits, in_row < 2^20)
__global__ void __launch_bounds__(256) fill_half(
    const int* __restrict__ out_map, const int* __restrict__ in_map,
    const u8* __restrict__ posb, const u32* __restrict__ bins,
    u32* __restrict__ entries, int rlo, int rhi)
{
    const int e = blockIdx.x * 256 + threadIdx.x;
    if (e >= TOTE) return;
    const int j = out_map[e];
    if (j < rlo || j >= rhi) return;
    const u32 base = bins[rlo];
    const u32 idx = bins[j] + (u32)posb[e] - base;
    const u32 k = (u32)(e / NPTS);
    entries[idx] = (k << 20) | (u32)in_map[e];
}

// ---------------- conv1 gather: Cin=1, f64 accumulate, zero atomics ----------------
// 16 lanes own one output row's 16 channels; one coalesced row write.
__global__ void __launch_bounds__(256) conv1_gather(
    const float* __restrict__ feats, const float* __restrict__ W1,
    const u32* __restrict__ entries, const u32* __restrict__ bins,
    int rlo, float* __restrict__ h1)
{
    __shared__ double w[KK * C];                 // 3456 B
    for (int u = threadIdx.x; u < KK * C; u += 256) w[u] = (double)W1[u];
    __syncthreads();
    const int g = threadIdx.x >> 4, c = threadIdx.x & 15;
    const int j = rlo + blockIdx.x * 16 + g;
    const u32 base = bins[rlo];
    u32 s = bins[j] - base;
    const u32 t = bins[j + 1] - base;
    double acc = 0.0;
    for (; s < t; ++s) {
        const u32 e = entries[s];                // same addr across 16 lanes -> broadcast
        const int r = (int)(e & 0xFFFFFu);
        const int k = (int)(e >> 20);
        acc += (double)feats[r] * w[k * C + c];
    }
    h1[(size_t)j * C + c] = (float)acc;
}

// ---------------- conv2 gather: 16->16, f64 accumulate, zero atomics ----------------
__global__ void __launch_bounds__(256) conv2_gather(
    const float* __restrict__ h1, const float* __restrict__ W2,
    const u32* __restrict__ entries, const u32* __restrict__ bins,
    int rlo, float* __restrict__ out2)
{
    __shared__ float w[KK * C * C];              // 27,648 B -> ~5 blocks/CU
    for (int u = threadIdx.x; u < KK * C * C; u += 256) w[u] = W2[u];
    __syncthreads();
    const int g = threadIdx.x >> 4, c = threadIdx.x & 15;
    const int j = rlo + blockIdx.x * 16 + g;
    const u32 base = bins[rlo];
    u32 s = bins[j] - base;
    const u32 t = bins[j + 1] - base;
    double acc = 0.0;
    for (; s < t; ++s) {
        const u32 e = entries[s];
        const int r = (int)(e & 0xFFFFFu);
        const int k = (int)(e >> 20);
        const float hv = h1[(size_t)r * C + c]; // coalesced 64 B per 16-lane group
        const float* wk = &w[k * C * C + c];
#pragma unroll
        for (int c1 = 0; c1 < C; ++c1)
            acc += (double)__shfl(hv, c1, 16) * (double)wk[c1 * C];
    }
    out2[(size_t)j * C + c] = (float)acc;
}

// ---------------- BN stats: f64 sum/sumsq per channel over f32 input ----------------
__global__ void __launch_bounds__(256) bn_stats_f32(
    const float* __restrict__ x, double* __restrict__ stats)
{
    double s[C], s2[C];
#pragma unroll
    for (int c = 0; c < C; ++c) { s[c] = 0.0; s2[c] = 0.0; }
    const int stride = gridDim.x * 256;
    for (int i = blockIdx.x * 256 + threadIdx.x; i < NPTS; i += stride) {
        const float4* rp = (const float4*)(x + (size_t)i * C);
        float v[C];
#pragma unroll
        for (int q = 0; q < 4; ++q) {
            const float4 d = rp[q];
            v[4*q] = d.x; v[4*q+1] = d.y; v[4*q+2] = d.z; v[4*q+3] = d.w;
        }
#pragma unroll
        for (int c = 0; c < C; ++c) { const double dv = v[c]; s[c] += dv; s2[c] += dv * dv; }
    }
#pragma unroll
    for (int c = 0; c < C; ++c) {
#pragma unroll
        for (int off = 32; off > 0; off >>= 1) {
            s[c]  += __shfl_down(s[c],  off, 64);
            s2[c] += __shfl_down(s2[c], off, 64);
        }
    }
    if ((threadIdx.x & 63) == 0) {
#pragma unroll
        for (int c = 0; c < C; ++c) {
            atomAddF64(&stats[c], s[c]);
            atomAddF64(&stats[C + c], s2[c]);
        }
    }
}

// ---------------- BN + ELU in place on f32 ----------------
__global__ void __launch_bounds__(256) bn_apply_f32(
    float* __restrict__ x, const double* __restrict__ stats,
    const float* __restrict__ gamma, const float* __restrict__ beta)
{
    __shared__ double sc[C], sh[C];
    if (threadIdx.x < C) {
        const int c = threadIdx.x;
        const double m = stats[c] / (double)NPTS;
        const double v = stats[C + c] / (double)NPTS - m * m;
        const double scale = (double)gamma[c] * rsqrt(v + 1e-5);
        sc[c] = scale;
        sh[c] = (double)beta[c] - m * scale;
    }
    __syncthreads();
    const size_t t = (size_t)blockIdx.x * 256 + threadIdx.x;
    if (t >= (size_t)NPTS * C) return;
    const int c = (int)(t & (C - 1));
    x[t] = (float)elu64((double)x[t] * sc[c] + sh[c]);
}

// ---------------- final: BN2 + ELU + cls + prune ----------------
__global__ void __launch_bounds__(256) final_f32(
    const float* __restrict__ x, const double* __restrict__ stats,
    const float* __restrict__ gamma, const float* __restrict__ beta,
    const float* __restrict__ Wcls, const float* __restrict__ bcls,
    float* __restrict__ out)
{
    __shared__ double sc[C], sh[C], wc[C];
    __shared__ double bc;
    if (threadIdx.x < C) {
        const int c = threadIdx.x;
        const double m = stats[c] / (double)NPTS;
        const double v = stats[C + c] / (double)NPTS - m * m;
        const double scale = (double)gamma[c] * rsqrt(v + 1e-5);
        sc[c] = scale;
        sh[c] = (double)beta[c] - m * scale;
        wc[c] = (double)Wcls[c];
    }
    if (threadIdx.x == 0) bc = (double)bcls[0];
    __syncthreads();
    const int i = blockIdx.x * 256 + threadIdx.x;
    if (i >= NPTS) return;
    const float4* rp = (const float4*)(x + (size_t)i * C);
    float v[C];
#pragma unroll
    for (int q = 0; q < 4; ++q) {
        const float4 d = rp[q];
        v[4*q] = d.x; v[4*q+1] = d.y; v[4*q+2] = d.z; v[4*q+3] = d.w;
    }
    double hh[C];
    double cls = bc;
#pragma unroll
    for (int c = 0; c < C; ++c) {
        const double e = elu64((double)v[c] * sc[c] + sh[c]);
        hh[c] = e;
        cls += e * wc[c];
    }
    const bool keep = cls > 0.0;
    float* row = out + (size_t)i * 17;
#pragma unroll
    for (int c = 0; c < C; ++c) row[c] = keep ? (float)hh[c] : 0.f;
    row[16] = (float)cls;
}

// =====================================================================
// Memory plan (ws proven >= 128,000,256 B; d_out = 68,000,000 B scratch
// until final_f32 overwrites it):
//   ws + 0          : h1   [N,16] f32   64,000,000 B
//   ws + 64,000,000 : out2 [N,16] f32   64,000,000 B
//   ws + 96,000,000 : posb u8           27,000,000 B  (overlaps out2 rows
//                     [500k,1M) — posb is dead before gather-half1 writes them)
//   ws + 128,000,000: stats 32 f64      256 B (reused for BN1 then BN2)
//   d_out + 0          : entries u32, cap 14M    56,000,000 B
//   d_out + 56,000,000 : bins u32 [N+1]           4,000,004 B
//   d_out + 60,000,512 : partials u32 [3907]         15,628 B
// All d_out scratch dies before final_f32 writes d_out[0 : 68,000,000).
// =====================================================================
extern "C" void kernel_launch(void* const* d_in, const int* in_sizes, int n_in,
                              void* d_out, int out_size, void* d_ws, size_t ws_size,
                              hipStream_t stream)
{
    const float* feats  = (const float*)d_in[0];
    const float* W1     = (const float*)d_in[1];
    const float* gamma1 = (const float*)d_in[2];
    const float* beta1  = (const float*)d_in[3];
    const float* W2     = (const float*)d_in[4];
    const float* gamma2 = (const float*)d_in[5];
    const float* beta2  = (const float*)d_in[6];
    const float* Wcls   = (const float*)d_in[7];
    const float* bcls   = (const float*)d_in[8];
    const int* in1 = (const int*)d_in[9];
    const int* om1 = (const int*)d_in[10];
    const int* in2 = (const int*)d_in[11];
    const int* om2 = (const int*)d_in[12];

    char* wsb = (char*)d_ws;
    float*  h1    = (float*)wsb;
    float*  out2  = (float*)(wsb + 64000000);
    u8*     posb  = (u8*)  (wsb + 96000000);
    double* stats = (double*)(wsb + 128000000);

    char* ob = (char*)d_out;
    u32* entries  = (u32*)ob;
    u32* bins     = (u32*)(ob + 56000000);
    u32* partials = (u32*)(ob + 60000512);

    const int GE = (TOTE + 255) / 256;   // 105,469 — entry-parallel kernels
    const int GR = HALF / 16;            // 31,250  — gather (16 rows/block)
    const int GA = (NPTS * C) / 256;     // 62,500  — elementwise
    const int GF = NBLK1;                // 3,907   — row-parallel

    // ---------------- conv1 ----------------
    hipMemsetAsync(bins, 0, (NPTS + 1) * sizeof(u32), stream);
    hist_pos<<<GE, 256, 0, stream>>>(om1, bins, posb);
    scan_k1<<<NBLK1, 256, 0, stream>>>(bins, partials);
    scan_k2<<<1, 256, 0, stream>>>(partials);
    scan_k3<<<NBLK1, 256, 0, stream>>>(bins, partials);
    for (int h = 0; h < 2; ++h) {
        const int rlo = h * HALF, rhi = rlo + HALF;
        fill_half<<<GE, 256, 0, stream>>>(om1, in1, posb, bins, entries, rlo, rhi);
        conv1_gather<<<GR, 256, 0, stream>>>(feats, W1, entries, bins, rlo, h1);
    }
    hipMemsetAsync(stats, 0, 32 * sizeof(double), stream);
    bn_stats_f32<<<1024, 256, 0, stream>>>(h1, stats);
    bn_apply_f32<<<GA, 256, 0, stream>>>(h1, stats, gamma1, beta1);

    // ---------------- conv2 ----------------
    hipMemsetAsync(bins, 0, (NPTS + 1) * sizeof(u32), stream);
    hist_pos<<<GE, 256, 0, stream>>>(om2, bins, posb);
    scan_k1<<<NBLK1, 256, 0, stream>>>(bins, partials);
    scan_k2<<<1, 256, 0, stream>>>(partials);
    scan_k3<<<NBLK1, 256, 0, stream>>>(bins, partials);
    for (int h = 0; h < 2; ++h) {
        const int rlo = h * HALF, rhi = rlo + HALF;
        fill_half<<<GE, 256, 0, stream>>>(om2, in2, posb, bins, entries, rlo, rhi);
        conv2_gather<<<GR, 256, 0, stream>>>(h1, W2, entries, bins, rlo, out2);
    }
    hipMemsetAsync(stats, 0, 32 * sizeof(double), stream);
    bn_stats_f32<<<1024, 256, 0, stream>>>(out2, stats);
    final_f32<<<GF, 256, 0, stream>>>(out2, stats, gamma2, beta2, Wcls, bcls, (float*)d_out);
}

// Round 2
// 8110.554 us; speedup vs baseline: 5.0295x; 1.0288x over previous
//
#include <hip/hip_runtime.h>

#define KK 27
#define NPTS 1000000
#define C 16
#define TOTE (KK * NPTS)        // 27,000,000 kernel-map entries per conv
#define HALF (NPTS / 2)         // output rows per processing half
#define NBLK1 3907              // ceil(NPTS/256) for the scan

typedef unsigned int u32;
typedef unsigned char u8;

__device__ __forceinline__ double elu64(double x) { return x > 0.0 ? x : expm1(x); }

__device__ __forceinline__ void atomAddF64(double* p, double v) {
#if defined(__gfx90a__) || defined(__gfx940__) || defined(__gfx941__) || defined(__gfx942__) || defined(__gfx950__)
    unsafeAtomicAdd(p, v);
#else
    atomicAdd(p, v);
#endif
}

// ---------------- binning: histogram + remember my slot (u8), 4 entries/thread ----------------
__global__ void __launch_bounds__(256) hist_pos(
    const int* __restrict__ out_map, u32* __restrict__ bins, u8* __restrict__ posb)
{
    const int e0 = (blockIdx.x * 256 + threadIdx.x) * 4;
    if (e0 >= TOTE) return;                       // TOTE % 4 == 0, full quads
    const int4 j4 = *(const int4*)(out_map + e0);
    // 4 independent atomics in flight (MLP on the return latency)
    const u32 p0 = atomicAdd(&bins[j4.x], 1u);
    const u32 p1 = atomicAdd(&bins[j4.y], 1u);
    const u32 p2 = atomicAdd(&bins[j4.z], 1u);
    const u32 p3 = atomicAdd(&bins[j4.w], 1u);
    uchar4 p; p.x = (u8)p0; p.y = (u8)p1; p.z = (u8)p2; p.w = (u8)p3;
    *(uchar4*)(posb + e0) = p;                    // bin sizes ~Poisson(27) << 255
}

// ---------------- exclusive scan of bins[0..NPTS) (3-kernel textbook) ----------------
__global__ void __launch_bounds__(256) scan_k1(u32* __restrict__ bins, u32* __restrict__ partials)
{
    __shared__ u32 sd[256];
    const int t = threadIdx.x;
    const int i = blockIdx.x * 256 + t;
    const u32 v = (i < NPTS) ? bins[i] : 0u;
    sd[t] = v;
    __syncthreads();
    for (int off = 1; off < 256; off <<= 1) {
        const u32 x = (t >= off) ? sd[t - off] : 0u;
        __syncthreads();
        sd[t] += x;
        __syncthreads();
    }
    if (i < NPTS) bins[i] = sd[t] - v;          // exclusive within block
    if (t == 255) partials[blockIdx.x] = sd[255];
}

__global__ void __launch_bounds__(256) scan_k2(u32* __restrict__ partials)
{
    __shared__ u32 sd[256];
    const int t = threadIdx.x;
    u32 loc[16];
    u32 sum = 0;
#pragma unroll
    for (int u = 0; u < 16; ++u) {
        const int idx = t * 16 + u;
        loc[u] = (idx < NBLK1) ? partials[idx] : 0u;
        sum += loc[u];
    }
    sd[t] = sum;
    __syncthreads();
    for (int off = 1; off < 256; off <<= 1) {
        const u32 x = (t >= off) ? sd[t - off] : 0u;
        __syncthreads();
        sd[t] += x;
        __syncthreads();
    }
    u32 run = sd[t] - sum;                      // exclusive chunk base
#pragma unroll
    for (int u = 0; u < 16; ++u) {
        const int idx = t * 16 + u;
        if (idx < NBLK1) partials[idx] = run;
        run += loc[u];
    }
}

__global__ void __launch_bounds__(256) scan_k3(u32* __restrict__ bins, const u32* __restrict__ partials)
{
    const int i = blockIdx.x * 256 + threadIdx.x;
    if (i < NPTS) bins[i] += partials[blockIdx.x];
    if (i == 0) bins[NPTS] = (u32)TOTE;
}

// ---------------- fill entries for output rows [rlo, rhi) — NO atomics ----------------
// entry = (k << 20) | in_row   (k < 27 -> 5 bits, in_row < 2^20)
__global__ void __launch_bounds__(256) fill_half(
    const int* __restrict__ out_map, const int* __restrict__ in_map,
    const u8* __restrict__ posb, const u32* __restrict__ bins,
    u32* __restrict__ entries, int rlo, int rhi)
{
    const int e = blockIdx.x * 256 + threadIdx.x;
    if (e >= TOTE) return;
    const int j = out_map[e];
    if (j < rlo || j >= rhi) return;
    const u32 base = bins[rlo];
    const u32 idx = bins[j] + (u32)posb[e] - base;
    const u32 k = (u32)(e / NPTS);
    entries[idx] = (k << 20) | (u32)in_map[e];
}

// ---------------- conv1 gather: Cin=1, f64 accumulate, zero atomics ----------------
__global__ void __launch_bounds__(256) conv1_gather(
    const float* __restrict__ feats, const float* __restrict__ W1,
    const u32* __restrict__ entries, const u32* __restrict__ bins,
    int rlo, float* __restrict__ h1)
{
    __shared__ double w[KK * C];                 // 3456 B
    for (int u = threadIdx.x; u < KK * C; u += 256) w[u] = (double)W1[u];
    __syncthreads();
    const int g = threadIdx.x >> 4, c = threadIdx.x & 15;
    const int j = rlo + blockIdx.x * 16 + g;
    const u32 base = bins[rlo];
    u32 s = bins[j] - base;
    const u32 t = bins[j + 1] - base;
    double acc = 0.0;
    for (; s < t; ++s) {
        const u32 e = entries[s];                // same addr across 16 lanes -> broadcast
        const int r = (int)(e & 0xFFFFFu);
        const int k = (int)(e >> 20);
        acc += (double)feats[r] * w[k * C + c];
    }
    h1[(size_t)j * C + c] = (float)acc;
}

// ---------------- conv2 gather v2: 16->16, f64 accumulate, zero atomics ----------------
// DS-pipe redesign: hv row comes from GLOBAL (group-uniform dwordx4 -> broadcast,
// VMEM pipe was idle); weights transposed in LDS so each lane reads its 16-weight
// column as 4x ds_read_b128.  Row pad 20 floats (2-way bank = free), k-stride 324
// words rotates banks across the 4 groups of a wave.  Same products, same order,
// same f64 accumulation as before -> bit-identical output.
#define WKS 324                                  // padded k-stride in floats
__global__ void __launch_bounds__(256) conv2_gather(
    const float* __restrict__ h1, const float* __restrict__ W2,
    const u32* __restrict__ entries, const u32* __restrict__ bins,
    int rlo, float* __restrict__ out2)
{
    __shared__ float wt[KK * WKS];               // 34,992 B -> 4 blocks/CU
    for (int u = threadIdx.x; u < KK * 256; u += 256) {
        const int k = u >> 8, r = u & 255, c1 = r >> 4, c2 = r & 15;
        wt[k * WKS + c2 * 20 + c1] = W2[u];      // transpose: wt[k][c2][c1]
    }
    __syncthreads();
    const int g = threadIdx.x >> 4, c = threadIdx.x & 15;
    const int j = rlo + blockIdx.x * 16 + g;
    const u32 base = bins[rlo];
    u32 s = bins[j] - base;
    const u32 t = bins[j + 1] - base;
    double acc = 0.0;
    const float* wbase = wt + c * 20;
    for (; s < t; ++s) {
        const u32 e = entries[s];                // group-uniform -> broadcast load
        const int r = (int)(e & 0xFFFFFu);
        const int k = (int)(e >> 20);
        const float4* hp = (const float4*)(h1 + (size_t)r * C);
        const float4 ha = hp[0], hb = hp[1], hc = hp[2], hd = hp[3];
        const float* wr = wbase + k * WKS;       // 16B-aligned (k*1296, c*80 bytes)
        const float4 wa = *(const float4*)(wr);
        const float4 wb = *(const float4*)(wr + 4);
        const float4 wc = *(const float4*)(wr + 8);
        const float4 wd = *(const float4*)(wr + 12);
        acc += (double)ha.x * (double)wa.x; acc += (double)ha.y * (double)wa.y;
        acc += (double)ha.z * (double)wa.z; acc += (double)ha.w * (double)wa.w;
        acc += (double)hb.x * (double)wb.x; acc += (double)hb.y * (double)wb.y;
        acc += (double)hb.z * (double)wb.z; acc += (double)hb.w * (double)wb.w;
        acc += (double)hc.x * (double)wc.x; acc += (double)hc.y * (double)wc.y;
        acc += (double)hc.z * (double)wc.z; acc += (double)hc.w * (double)wc.w;
        acc += (double)hd.x * (double)wd.x; acc += (double)hd.y * (double)wd.y;
        acc += (double)hd.z * (double)wd.z; acc += (double)hd.w * (double)wd.w;
    }
    out2[(size_t)j * C + c] = (float)acc;
}

// ---------------- BN stats: f64 sum/sumsq per channel over f32 input ----------------
__global__ void __launch_bounds__(256) bn_stats_f32(
    const float* __restrict__ x, double* __restrict__ stats)
{
    double s[C], s2[C];
#pragma unroll
    for (int c = 0; c < C; ++c) { s[c] = 0.0; s2[c] = 0.0; }
    const int stride = gridDim.x * 256;
    for (int i = blockIdx.x * 256 + threadIdx.x; i < NPTS; i += stride) {
        const float4* rp = (const float4*)(x + (size_t)i * C);
        float v[C];
#pragma unroll
        for (int q = 0; q < 4; ++q) {
            const float4 d = rp[q];
            v[4*q] = d.x; v[4*q+1] = d.y; v[4*q+2] = d.z; v[4*q+3] = d.w;
        }
#pragma unroll
        for (int c = 0; c < C; ++c) { const double dv = v[c]; s[c] += dv; s2[c] += dv * dv; }
    }
#pragma unroll
    for (int c = 0; c < C; ++c) {
#pragma unroll
        for (int off = 32; off > 0; off >>= 1) {
            s[c]  += __shfl_down(s[c],  off, 64);
            s2[c] += __shfl_down(s2[c], off, 64);
        }
    }
    if ((threadIdx.x & 63) == 0) {
#pragma unroll
        for (int c = 0; c < C; ++c) {
            atomAddF64(&stats[c], s[c]);
            atomAddF64(&stats[C + c], s2[c]);
        }
    }
}

// ---------------- BN + ELU in place on f32 ----------------
__global__ void __launch_bounds__(256) bn_apply_f32(
    float* __restrict__ x, const double* __restrict__ stats,
    const float* __restrict__ gamma, const float* __restrict__ beta)
{
    __shared__ double sc[C], sh[C];
    if (threadIdx.x < C) {
        const int c = threadIdx.x;
        const double m = stats[c] / (double)NPTS;
        const double v = stats[C + c] / (double)NPTS - m * m;
        const double scale = (double)gamma[c] * rsqrt(v + 1e-5);
        sc[c] = scale;
        sh[c] = (double)beta[c] - m * scale;
    }
    __syncthreads();
    const size_t t = (size_t)blockIdx.x * 256 + threadIdx.x;
    if (t >= (size_t)NPTS * C) return;
    const int c = (int)(t & (C - 1));
    x[t] = (float)elu64((double)x[t] * sc[c] + sh[c]);
}

// ---------------- final: BN2 + ELU + cls + prune ----------------
__global__ void __launch_bounds__(256) final_f32(
    const float* __restrict__ x, const double* __restrict__ stats,
    const float* __restrict__ gamma, const float* __restrict__ beta,
    const float* __restrict__ Wcls, const float* __restrict__ bcls,
    float* __restrict__ out)
{
    __shared__ double sc[C], sh[C], wc[C];
    __shared__ double bc;
    if (threadIdx.x < C) {
        const int c = threadIdx.x;
        const double m = stats[c] / (double)NPTS;
        const double v = stats[C + c] / (double)NPTS - m * m;
        const double scale = (double)gamma[c] * rsqrt(v + 1e-5);
        sc[c] = scale;
        sh[c] = (double)beta[c] - m * scale;
        wc[c] = (double)Wcls[c];
    }
    if (threadIdx.x == 0) bc = (double)bcls[0];
    __syncthreads();
    const int i = blockIdx.x * 256 + threadIdx.x;
    if (i >= NPTS) return;
    const float4* rp = (const float4*)(x + (size_t)i * C);
    float v[C];
#pragma unroll
    for (int q = 0; q < 4; ++q) {
        const float4 d = rp[q];
        v[4*q] = d.x; v[4*q+1] = d.y; v[4*q+2] = d.z; v[4*q+3] = d.w;
    }
    double hh[C];
    double cls = bc;
#pragma unroll
    for (int c = 0; c < C; ++c) {
        const double e = elu64((double)v[c] * sc[c] + sh[c]);
        hh[c] = e;
        cls += e * wc[c];
    }
    const bool keep = cls > 0.0;
    float* row = out + (size_t)i * 17;
#pragma unroll
    for (int c = 0; c < C; ++c) row[c] = keep ? (float)hh[c] : 0.f;
    row[16] = (float)cls;
}

// =====================================================================
// Memory plan (ws proven >= 128,000,256 B; d_out = 68,000,000 B scratch
// until final_f32 overwrites it):
//   ws + 0          : h1   [N,16] f32   64,000,000 B
//   ws + 64,000,000 : out2 [N,16] f32   64,000,000 B
//   ws + 96,000,000 : posb u8           27,000,000 B  (overlaps out2 rows
//                     [500k,1M) — posb is dead before gather-half1 writes them)
//   ws + 128,000,000: stats 32 f64      256 B (reused for BN1 then BN2)
//   d_out + 0          : entries u32, cap 14M    56,000,000 B
//   d_out + 56,000,000 : bins u32 [N+1]           4,000,004 B
//   d_out + 60,000,512 : partials u32 [3907]         15,628 B
// All d_out scratch dies before final_f32 writes d_out[0 : 68,000,000).
// =====================================================================
extern "C" void kernel_launch(void* const* d_in, const int* in_sizes, int n_in,
                              void* d_out, int out_size, void* d_ws, size_t ws_size,
                              hipStream_t stream)
{
    const float* feats  = (const float*)d_in[0];
    const float* W1     = (const float*)d_in[1];
    const float* gamma1 = (const float*)d_in[2];
    const float* beta1  = (const float*)d_in[3];
    const float* W2     = (const float*)d_in[4];
    const float* gamma2 = (const float*)d_in[5];
    const float* beta2  = (const float*)d_in[6];
    const float* Wcls   = (const float*)d_in[7];
    const float* bcls   = (const float*)d_in[8];
    const int* in1 = (const int*)d_in[9];
    const int* om1 = (const int*)d_in[10];
    const int* in2 = (const int*)d_in[11];
    const int* om2 = (const int*)d_in[12];

    char* wsb = (char*)d_ws;
    float*  h1    = (float*)wsb;
    float*  out2  = (float*)(wsb + 64000000);
    u8*     posb  = (u8*)  (wsb + 96000000);
    double* stats = (double*)(wsb + 128000000);

    char* ob = (char*)d_out;
    u32* entries  = (u32*)ob;
    u32* bins     = (u32*)(ob + 56000000);
    u32* partials = (u32*)(ob + 60000512);

    const int GE = (TOTE + 255) / 256;       // 105,469 — entry-parallel kernels
    const int GH = (TOTE / 4 + 255) / 256;   // 26,368  — hist (4 entries/thread)
    const int GR = HALF / 16;                // 31,250  — gather (16 rows/block)
    const int GA = (NPTS * C) / 256;         // 62,500  — elementwise
    const int GF = NBLK1;                    // 3,907   — row-parallel

    // ---------------- conv1 ----------------
    hipMemsetAsync(bins, 0, (NPTS + 1) * sizeof(u32), stream);
    hist_pos<<<GH, 256, 0, stream>>>(om1, bins, posb);
    scan_k1<<<NBLK1, 256, 0, stream>>>(bins, partials);
    scan_k2<<<1, 256, 0, stream>>>(partials);
    scan_k3<<<NBLK1, 256, 0, stream>>>(bins, partials);
    for (int h = 0; h < 2; ++h) {
        const int rlo = h * HALF, rhi = rlo + HALF;
        fill_half<<<GE, 256, 0, stream>>>(om1, in1, posb, bins, entries, rlo, rhi);
        conv1_gather<<<GR, 256, 0, stream>>>(feats, W1, entries, bins, rlo, h1);
    }
    hipMemsetAsync(stats, 0, 32 * sizeof(double), stream);
    bn_stats_f32<<<1024, 256, 0, stream>>>(h1, stats);
    bn_apply_f32<<<GA, 256, 0, stream>>>(h1, stats, gamma1, beta1);

    // ---------------- conv2 ----------------
    hipMemsetAsync(bins, 0, (NPTS + 1) * sizeof(u32), stream);
    hist_pos<<<GH, 256, 0, stream>>>(om2, bins, posb);
    scan_k1<<<NBLK1, 256, 0, stream>>>(bins, partials);
    scan_k2<<<1, 256, 0, stream>>>(partials);
    scan_k3<<<NBLK1, 256, 0, stream>>>(bins, partials);
    for (int h = 0; h < 2; ++h) {
        const int rlo = h * HALF, rhi = rlo + HALF;
        fill_half<<<GE, 256, 0, stream>>>(om2, in2, posb, bins, entries, rlo, rhi);
        conv2_gather<<<GR, 256, 0, stream>>>(h1, W2, entries, bins, rlo, out2);
    }
    hipMemsetAsync(stats, 0, 32 * sizeof(double), stream);
    bn_stats_f32<<<1024, 256, 0, stream>>>(out2, stats);
    final_f32<<<GF, 256, 0, stream>>>(out2, stats, gamma2, beta2, Wcls, bcls, (float*)d_out);
}

// Round 3
// 5976.545 us; speedup vs baseline: 6.8253x; 1.3571x over previous
//
#include <hip/hip_runtime.h>

#define KK 27
#define NPTS 1000000
#define C 16
#define TOTE (KK * NPTS)        // 27,000,000 kernel-map entries per conv
#define SEG 64                  // rows per bucket
#define NBUCK 15625             // NPTS / SEG
#define NBPAD 15872             // 62*256, scan padding
#define SBLK 62                 // scan blocks over NBPAD
#define NBLKA 216               // partition blocks
#define EPB 125000              // TOTE / NBLKA (exact)
#define B1 7812                 // buckets in half1
#define R1 499968               // rows in half1 = B1*SEG
#define BCAP 2176               // rowsort LDS entry capacity (avg 1728, +10σ safe)
#define NBLK1 3907              // ceil(NPTS/256)

typedef unsigned int u32;

__device__ __forceinline__ double elu64(double x) { return x > 0.0 ? x : expm1(x); }

__device__ __forceinline__ void atomAddF64(double* p, double v) {
#if defined(__gfx90a__) || defined(__gfx940__) || defined(__gfx941__) || defined(__gfx942__) || defined(__gfx950__)
    unsafeAtomicAdd(p, v);
#else
    atomicAdd(p, v);
#endif
}

// ================= atomic-free counting sort (replaces hist_pos/fill) =================

// A1: per-block LDS histogram over 15625 buckets (j>>6). No global atomics.
__global__ void __launch_bounds__(256) part_hist(
    const int* __restrict__ om, u32* __restrict__ counts)
{
    __shared__ u32 h[NBUCK];                    // 62,500 B
    for (int u = threadIdx.x; u < NBUCK; u += 256) h[u] = 0u;
    __syncthreads();
    const int lo = blockIdx.x * EPB, hi = lo + EPB;
    for (int e = lo + threadIdx.x * 4; e < hi; e += 1024) {
        const int4 j4 = *(const int4*)(om + e);
        atomicAdd(&h[j4.x >> 6], 1u);
        atomicAdd(&h[j4.y >> 6], 1u);
        atomicAdd(&h[j4.z >> 6], 1u);
        atomicAdd(&h[j4.w >> 6], 1u);
    }
    __syncthreads();
    u32* cb = counts + (size_t)blockIdx.x * NBUCK;
    for (int u = threadIdx.x; u < NBUCK; u += 256) cb[u] = h[u];
}

// S1: totals[b] = sum over blocks of counts[blk][b]  (coalesced across threads)
__global__ void __launch_bounds__(256) sum_cols(
    const u32* __restrict__ counts, u32* __restrict__ totals)
{
    const int b = blockIdx.x * 256 + threadIdx.x;
    u32 s = 0;
    if (b < NBUCK)
        for (int blk = 0; blk < NBLKA; ++blk) s += counts[(size_t)blk * NBUCK + b];
    totals[b] = s;                               // pad [NBUCK,NBPAD) stays 0
}

// exclusive scan of totals[0..NBPAD)
__global__ void __launch_bounds__(256) scanT_k1(u32* __restrict__ a, u32* __restrict__ pt)
{
    __shared__ u32 sd[256];
    const int t = threadIdx.x;
    const int i = blockIdx.x * 256 + t;
    const u32 v = a[i];
    sd[t] = v; __syncthreads();
    for (int off = 1; off < 256; off <<= 1) {
        const u32 x = (t >= off) ? sd[t - off] : 0u;
        __syncthreads(); sd[t] += x; __syncthreads();
    }
    a[i] = sd[t] - v;
    if (t == 255) pt[blockIdx.x] = sd[255];
}
__global__ void scanT_k2(u32* __restrict__ pt)
{
    if (threadIdx.x == 0) {
        u32 run = 0;
        for (int i = 0; i < SBLK; ++i) { const u32 c = pt[i]; pt[i] = run; run += c; }
    }
}
__global__ void __launch_bounds__(256) scanT_k3(u32* __restrict__ a, const u32* __restrict__ pt)
{
    const int i = blockIdx.x * 256 + threadIdx.x;
    a[i] += pt[blockIdx.x];
}

// S3: counts[blk][b] <- global base for (blk,bucket); seed sentinel bins.
__global__ void __launch_bounds__(256) make_bases(
    u32* __restrict__ counts, const u32* __restrict__ totals, u32* __restrict__ bins)
{
    const int b = blockIdx.x * 256 + threadIdx.x;
    if (b == 0) { bins[NPTS] = (u32)TOTE; bins[R1] = totals[B1]; }
    if (b >= NBUCK) return;
    u32 run = totals[b];
    for (int blk = 0; blk < NBLKA; ++blk) {
        const size_t idx = (size_t)blk * NBUCK + b;
        const u32 c = counts[idx];
        counts[idx] = run;
        run += c;
    }
}

// A2: scatter entries of buckets [blo,bhi) to bucket-partitioned order.
// entry = (jlo6 << 25) | (k5 << 20) | r20.  LDS-local base bumps (no global atomics).
__global__ void __launch_bounds__(256) part_scatter(
    const int* __restrict__ om, const int* __restrict__ im,
    const u32* __restrict__ counts, const u32* __restrict__ totals,
    u32* __restrict__ entries, int blo, int bhi)
{
    __shared__ u32 base[NBUCK];                 // 62,500 B
    const u32* cb = counts + (size_t)blockIdx.x * NBUCK;
    for (int u = threadIdx.x; u < NBUCK; u += 256) base[u] = cb[u];
    __syncthreads();
    const u32 halfoff = totals[blo];            // totals[0] == 0 for half1
    const int lo = blockIdx.x * EPB, hi = lo + EPB;
    for (int e = lo + threadIdx.x * 4; e < hi; e += 1024) {
        const int4 j4 = *(const int4*)(om + e);
        const int4 r4 = *(const int4*)(im + e);
        const u32 k = (u32)(e / NPTS);          // e..e+3 share k (both %4==0)
        const int jj[4] = { j4.x, j4.y, j4.z, j4.w };
        const int rr[4] = { r4.x, r4.y, r4.z, r4.w };
#pragma unroll
        for (int u = 0; u < 4; ++u) {
            const int b = jj[u] >> 6;
            if (b >= blo && b < bhi) {
                const u32 p = atomicAdd(&base[b], 1u);
                entries[p - halfoff] =
                    ((u32)(jj[u] & 63) << 25) | (k << 20) | (u32)rr[u];
            }
        }
    }
}

// B: row-sort each bucket in place (LDS) and emit bins[j] (global CSR values).
__global__ void __launch_bounds__(256) rowsort(
    u32* __restrict__ entries, const u32* __restrict__ totals,
    u32* __restrict__ bins, int blo)
{
    __shared__ u32 ebuf[BCAP];
    __shared__ u32 rowst[SEG], rowpos[SEG];
    const int b = blo + blockIdx.x;
    const u32 halfoff = totals[blo];
    const u32 glo = totals[b];
    const u32 n0 = totals[b + 1] - glo;
    const u32 n = n0 < BCAP ? n0 : (u32)BCAP;
    const u32 lo = glo - halfoff;
    if (threadIdx.x < SEG) rowpos[threadIdx.x] = 0u;
    __syncthreads();
    for (u32 i = threadIdx.x; i < n; i += 256) {
        const u32 e = entries[lo + i];
        ebuf[i] = e;
        atomicAdd(&rowpos[(e >> 25) & 63], 1u);
    }
    __syncthreads();
    if (threadIdx.x == 0) {
        u32 run = 0;
        for (int t = 0; t < SEG; ++t) { const u32 c = rowpos[t]; rowst[t] = run; run += c; }
    }
    __syncthreads();
    if (threadIdx.x < SEG) {
        bins[b * SEG + threadIdx.x] = glo + rowst[threadIdx.x];
        rowpos[threadIdx.x] = rowst[threadIdx.x];
    }
    __syncthreads();
    for (u32 i = threadIdx.x; i < n; i += 256) {
        const u32 e = ebuf[i];
        const u32 p = atomicAdd(&rowpos[(e >> 25) & 63], 1u);
        entries[lo + p] = e & 0x1FFFFFFu;       // strip jlo -> (k<<20)|r
    }
}

// ================= gather / BN / final (unchanged numerics) =================

__global__ void __launch_bounds__(256) conv1_gather(
    const float* __restrict__ feats, const float* __restrict__ W1,
    const u32* __restrict__ entries, const u32* __restrict__ bins,
    int rlo, float* __restrict__ h1)
{
    __shared__ double w[KK * C];
    for (int u = threadIdx.x; u < KK * C; u += 256) w[u] = (double)W1[u];
    __syncthreads();
    const int g = threadIdx.x >> 4, c = threadIdx.x & 15;
    const int j = rlo + blockIdx.x * 16 + g;
    const u32 base = bins[rlo];
    u32 s = bins[j] - base;
    const u32 t = bins[j + 1] - base;
    double acc = 0.0;
    for (; s < t; ++s) {
        const u32 e = entries[s];
        const int r = (int)(e & 0xFFFFFu);
        const int k = (int)(e >> 20);
        acc += (double)feats[r] * w[k * C + c];
    }
    h1[(size_t)j * C + c] = (float)acc;
}

#define WKS 324
__global__ void __launch_bounds__(256) conv2_gather(
    const float* __restrict__ h1, const float* __restrict__ W2,
    const u32* __restrict__ entries, const u32* __restrict__ bins,
    int rlo, float* __restrict__ out2)
{
    __shared__ float wt[KK * WKS];
    for (int u = threadIdx.x; u < KK * 256; u += 256) {
        const int k = u >> 8, r = u & 255, c1 = r >> 4, c2 = r & 15;
        wt[k * WKS + c2 * 20 + c1] = W2[u];
    }
    __syncthreads();
    const int g = threadIdx.x >> 4, c = threadIdx.x & 15;
    const int j = rlo + blockIdx.x * 16 + g;
    const u32 base = bins[rlo];
    u32 s = bins[j] - base;
    const u32 t = bins[j + 1] - base;
    double acc = 0.0;
    const float* wbase = wt + c * 20;
    for (; s < t; ++s) {
        const u32 e = entries[s];
        const int r = (int)(e & 0xFFFFFu);
        const int k = (int)(e >> 20);
        const float4* hp = (const float4*)(h1 + (size_t)r * C);
        const float4 ha = hp[0], hb = hp[1], hc = hp[2], hd = hp[3];
        const float* wr = wbase + k * WKS;
        const float4 wa = *(const float4*)(wr);
        const float4 wb = *(const float4*)(wr + 4);
        const float4 wc = *(const float4*)(wr + 8);
        const float4 wd = *(const float4*)(wr + 12);
        acc += (double)ha.x * (double)wa.x; acc += (double)ha.y * (double)wa.y;
        acc += (double)ha.z * (double)wa.z; acc += (double)ha.w * (double)wa.w;
        acc += (double)hb.x * (double)wb.x; acc += (double)hb.y * (double)wb.y;
        acc += (double)hb.z * (double)wb.z; acc += (double)hb.w * (double)wb.w;
        acc += (double)hc.x * (double)wc.x; acc += (double)hc.y * (double)wc.y;
        acc += (double)hc.z * (double)wc.z; acc += (double)hc.w * (double)wc.w;
        acc += (double)hd.x * (double)wd.x; acc += (double)hd.y * (double)wd.y;
        acc += (double)hd.z * (double)wd.z; acc += (double)hd.w * (double)wd.w;
    }
    out2[(size_t)j * C + c] = (float)acc;
}

__global__ void __launch_bounds__(256) bn_stats_f32(
    const float* __restrict__ x, double* __restrict__ stats)
{
    double s[C], s2[C];
#pragma unroll
    for (int c = 0; c < C; ++c) { s[c] = 0.0; s2[c] = 0.0; }
    const int stride = gridDim.x * 256;
    for (int i = blockIdx.x * 256 + threadIdx.x; i < NPTS; i += stride) {
        const float4* rp = (const float4*)(x + (size_t)i * C);
        float v[C];
#pragma unroll
        for (int q = 0; q < 4; ++q) {
            const float4 d = rp[q];
            v[4*q] = d.x; v[4*q+1] = d.y; v[4*q+2] = d.z; v[4*q+3] = d.w;
        }
#pragma unroll
        for (int c = 0; c < C; ++c) { const double dv = v[c]; s[c] += dv; s2[c] += dv * dv; }
    }
#pragma unroll
    for (int c = 0; c < C; ++c) {
#pragma unroll
        for (int off = 32; off > 0; off >>= 1) {
            s[c]  += __shfl_down(s[c],  off, 64);
            s2[c] += __shfl_down(s2[c], off, 64);
        }
    }
    if ((threadIdx.x & 63) == 0) {
#pragma unroll
        for (int c = 0; c < C; ++c) {
            atomAddF64(&stats[c], s[c]);
            atomAddF64(&stats[C + c], s2[c]);
        }
    }
}

__global__ void __launch_bounds__(256) bn_apply_f32(
    float* __restrict__ x, const double* __restrict__ stats,
    const float* __restrict__ gamma, const float* __restrict__ beta)
{
    __shared__ double sc[C], sh[C];
    if (threadIdx.x < C) {
        const int c = threadIdx.x;
        const double m = stats[c] / (double)NPTS;
        const double v = stats[C + c] / (double)NPTS - m * m;
        const double scale = (double)gamma[c] * rsqrt(v + 1e-5);
        sc[c] = scale;
        sh[c] = (double)beta[c] - m * scale;
    }
    __syncthreads();
    const size_t t = (size_t)blockIdx.x * 256 + threadIdx.x;
    if (t >= (size_t)NPTS * C) return;
    const int c = (int)(t & (C - 1));
    x[t] = (float)elu64((double)x[t] * sc[c] + sh[c]);
}

__global__ void __launch_bounds__(256) final_f32(
    const float* __restrict__ x, const double* __restrict__ stats,
    const float* __restrict__ gamma, const float* __restrict__ beta,
    const float* __restrict__ Wcls, const float* __restrict__ bcls,
    float* __restrict__ out)
{
    __shared__ double sc[C], sh[C], wc[C];
    __shared__ double bc;
    if (threadIdx.x < C) {
        const int c = threadIdx.x;
        const double m = stats[c] / (double)NPTS;
        const double v = stats[C + c] / (double)NPTS - m * m;
        const double scale = (double)gamma[c] * rsqrt(v + 1e-5);
        sc[c] = scale;
        sh[c] = (double)beta[c] - m * scale;
        wc[c] = (double)Wcls[c];
    }
    if (threadIdx.x == 0) bc = (double)bcls[0];
    __syncthreads();
    const int i = blockIdx.x * 256 + threadIdx.x;
    if (i >= NPTS) return;
    const float4* rp = (const float4*)(x + (size_t)i * C);
    float v[C];
#pragma unroll
    for (int q = 0; q < 4; ++q) {
        const float4 d = rp[q];
        v[4*q] = d.x; v[4*q+1] = d.y; v[4*q+2] = d.z; v[4*q+3] = d.w;
    }
    double hh[C];
    double cls = bc;
#pragma unroll
    for (int c = 0; c < C; ++c) {
        const double e = elu64((double)v[c] * sc[c] + sh[c]);
        hh[c] = e;
        cls += e * wc[c];
    }
    const bool keep = cls > 0.0;
    float* row = out + (size_t)i * 17;
#pragma unroll
    for (int c = 0; c < C; ++c) row[c] = keep ? (float)hh[c] : 0.f;
    row[16] = (float)cls;
}

// =====================================================================
// Memory plan (ws proven >= 128,000,256 B; d_out = 68,000,000 B scratch
// until final_f32 overwrites it):
//   ws + 0           : h1   [N,16] f32        64,000,000 B
//   ws + 64,000,000  : out2 [N,16] f32        64,000,000 B  (written only by gather2)
//   ws + 114,000,000 : counts u32[216*15625]  13,500,000 B  (dies before gather2-h2
//                      writes out2 rows >= R1, i.e. ws bytes >= 95,997,952)
//   ws + 127,500,000 : totals u32[15872]          63,488 B
//   ws + 127,563,488 : pt     u32[62]                248 B
//   ws + 128,000,000 : stats  f64[32]               256 B
//   d_out + 0          : entries u32 cap 14M   56,000,000 B (per half <=13.52M)
//   d_out + 56,000,000 : bins u32[N+1]          4,000,004 B
// Ordering guarantees: sort-h2 (reads counts) precedes gather2-h2 (clobbers it);
// gather-h1 reads bins[0..R1] (rowsort-h1 + make_bases seed bins[R1]).
// =====================================================================
extern "C" void kernel_launch(void* const* d_in, const int* in_sizes, int n_in,
                              void* d_out, int out_size, void* d_ws, size_t ws_size,
                              hipStream_t stream)
{
    const float* feats  = (const float*)d_in[0];
    const float* W1     = (const float*)d_in[1];
    const float* gamma1 = (const float*)d_in[2];
    const float* beta1  = (const float*)d_in[3];
    const float* W2     = (const float*)d_in[4];
    const float* gamma2 = (const float*)d_in[5];
    const float* beta2  = (const float*)d_in[6];
    const float* Wcls   = (const float*)d_in[7];
    const float* bcls   = (const float*)d_in[8];
    const int* in1 = (const int*)d_in[9];
    const int* om1 = (const int*)d_in[10];
    const int* in2 = (const int*)d_in[11];
    const int* om2 = (const int*)d_in[12];

    char* wsb = (char*)d_ws;
    float*  h1     = (float*)wsb;
    float*  out2   = (float*)(wsb + 64000000);
    u32*    counts = (u32*)(wsb + 114000000);
    u32*    totals = (u32*)(wsb + 127500000);
    u32*    pt     = (u32*)(wsb + 127563488);
    double* stats  = (double*)(wsb + 128000000);

    u32* entries = (u32*)d_out;
    u32* bins    = (u32*)((char*)d_out + 56000000);

    const int GA = (NPTS * C) / 256;        // 62,500
    const int G1 = R1 / 16;                 // 31,248 (half1 gather)
    const int G2 = (NPTS - R1) / 16;        // 31,252 (half2 gather)

    // ---------------- conv1: sort + gather ----------------
    part_hist<<<NBLKA, 256, 0, stream>>>(om1, counts);
    sum_cols<<<SBLK, 256, 0, stream>>>(counts, totals);
    scanT_k1<<<SBLK, 256, 0, stream>>>(totals, pt);
    scanT_k2<<<1, 64, 0, stream>>>(pt);
    scanT_k3<<<SBLK, 256, 0, stream>>>(totals, pt);
    make_bases<<<SBLK, 256, 0, stream>>>(counts, totals, bins);
    part_scatter<<<NBLKA, 256, 0, stream>>>(om1, in1, counts, totals, entries, 0, B1);
    rowsort<<<B1, 256, 0, stream>>>(entries, totals, bins, 0);
    conv1_gather<<<G1, 256, 0, stream>>>(feats, W1, entries, bins, 0, h1);
    part_scatter<<<NBLKA, 256, 0, stream>>>(om1, in1, counts, totals, entries, B1, NBUCK);
    rowsort<<<NBUCK - B1, 256, 0, stream>>>(entries, totals, bins, B1);
    conv1_gather<<<G2, 256, 0, stream>>>(feats, W1, entries, bins, R1, h1);

    hipMemsetAsync(stats, 0, 32 * sizeof(double), stream);
    bn_stats_f32<<<1024, 256, 0, stream>>>(h1, stats);
    bn_apply_f32<<<GA, 256, 0, stream>>>(h1, stats, gamma1, beta1);

    // ---------------- conv2: sort + gather ----------------
    part_hist<<<NBLKA, 256, 0, stream>>>(om2, counts);
    sum_cols<<<SBLK, 256, 0, stream>>>(counts, totals);
    scanT_k1<<<SBLK, 256, 0, stream>>>(totals, pt);
    scanT_k2<<<1, 64, 0, stream>>>(pt);
    scanT_k3<<<SBLK, 256, 0, stream>>>(totals, pt);
    make_bases<<<SBLK, 256, 0, stream>>>(counts, totals, bins);
    part_scatter<<<NBLKA, 256, 0, stream>>>(om2, in2, counts, totals, entries, 0, B1);
    rowsort<<<B1, 256, 0, stream>>>(entries, totals, bins, 0);
    conv2_gather<<<G1, 256, 0, stream>>>(h1, W2, entries, bins, 0, out2);
    part_scatter<<<NBLKA, 256, 0, stream>>>(om2, in2, counts, totals, entries, B1, NBUCK);
    rowsort<<<NBUCK - B1, 256, 0, stream>>>(entries, totals, bins, B1);
    conv2_gather<<<G2, 256, 0, stream>>>(h1, W2, entries, bins, R1, out2);

    hipMemsetAsync(stats, 0, 32 * sizeof(double), stream);
    bn_stats_f32<<<1024, 256, 0, stream>>>(out2, stats);
    final_f32<<<NBLK1, 256, 0, stream>>>(out2, stats, gamma2, beta2, Wcls, bcls, (float*)d_out);
}

// Round 4
// 5836.946 us; speedup vs baseline: 6.9885x; 1.0239x over previous
//
#include <hip/hip_runtime.h>

#define KK 27
#define NPTS 1000000
#define C 16
#define TOTE (KK * NPTS)        // 27,000,000 kernel-map entries per conv
#define SEG 64                  // rows per bucket
#define NBUCK 15625             // NPTS / SEG
#define NBPAD 15872             // 62*256, scan padding
#define SBLK 62                 // scan blocks over NBPAD
#define NBLKA 216               // partition blocks
#define EPB 125000              // TOTE / NBLKA (exact)
#define B1 7812                 // buckets in half1
#define R1 499968               // rows in half1 = B1*SEG
#define BCAP 2176               // rowsort LDS entry capacity (avg 1728, +10σ safe)
#define NBLK1 3907              // ceil(NPTS/256)

typedef unsigned int u32;

__device__ __forceinline__ double elu64(double x) { return x > 0.0 ? x : expm1(x); }

__device__ __forceinline__ void atomAddF64(double* p, double v) {
#if defined(__gfx90a__) || defined(__gfx940__) || defined(__gfx941__) || defined(__gfx942__) || defined(__gfx950__)
    unsafeAtomicAdd(p, v);
#else
    atomicAdd(p, v);
#endif
}

// ================= atomic-free counting sort (replaces hist_pos/fill) =================

// A1: per-block LDS histogram over 15625 buckets (j>>6). No global atomics.
__global__ void __launch_bounds__(256) part_hist(
    const int* __restrict__ om, u32* __restrict__ counts)
{
    __shared__ u32 h[NBUCK];                    // 62,500 B
    for (int u = threadIdx.x; u < NBUCK; u += 256) h[u] = 0u;
    __syncthreads();
    const int lo = blockIdx.x * EPB, hi = lo + EPB;
    for (int e = lo + threadIdx.x * 4; e < hi; e += 1024) {
        const int4 j4 = *(const int4*)(om + e);
        atomicAdd(&h[j4.x >> 6], 1u);
        atomicAdd(&h[j4.y >> 6], 1u);
        atomicAdd(&h[j4.z >> 6], 1u);
        atomicAdd(&h[j4.w >> 6], 1u);
    }
    __syncthreads();
    u32* cb = counts + (size_t)blockIdx.x * NBUCK;
    for (int u = threadIdx.x; u < NBUCK; u += 256) cb[u] = h[u];
}

// S1: totals[b] = sum over blocks of counts[blk][b]  (coalesced across threads)
__global__ void __launch_bounds__(256) sum_cols(
    const u32* __restrict__ counts, u32* __restrict__ totals)
{
    const int b = blockIdx.x * 256 + threadIdx.x;
    u32 s = 0;
    if (b < NBUCK)
        for (int blk = 0; blk < NBLKA; ++blk) s += counts[(size_t)blk * NBUCK + b];
    totals[b] = s;                               // pad [NBUCK,NBPAD) stays 0
}

// exclusive scan of totals[0..NBPAD)
__global__ void __launch_bounds__(256) scanT_k1(u32* __restrict__ a, u32* __restrict__ pt)
{
    __shared__ u32 sd[256];
    const int t = threadIdx.x;
    const int i = blockIdx.x * 256 + t;
    const u32 v = a[i];
    sd[t] = v; __syncthreads();
    for (int off = 1; off < 256; off <<= 1) {
        const u32 x = (t >= off) ? sd[t - off] : 0u;
        __syncthreads(); sd[t] += x; __syncthreads();
    }
    a[i] = sd[t] - v;
    if (t == 255) pt[blockIdx.x] = sd[255];
}
__global__ void scanT_k2(u32* __restrict__ pt)
{
    if (threadIdx.x == 0) {
        u32 run = 0;
        for (int i = 0; i < SBLK; ++i) { const u32 c = pt[i]; pt[i] = run; run += c; }
    }
}
__global__ void __launch_bounds__(256) scanT_k3(u32* __restrict__ a, const u32* __restrict__ pt)
{
    const int i = blockIdx.x * 256 + threadIdx.x;
    a[i] += pt[blockIdx.x];
}

// S3: counts[blk][b] <- global base for (blk,bucket); seed sentinel bins.
__global__ void __launch_bounds__(256) make_bases(
    u32* __restrict__ counts, const u32* __restrict__ totals, u32* __restrict__ bins)
{
    const int b = blockIdx.x * 256 + threadIdx.x;
    if (b == 0) { bins[NPTS] = (u32)TOTE; bins[R1] = totals[B1]; }
    if (b >= NBUCK) return;
    u32 run = totals[b];
    for (int blk = 0; blk < NBLKA; ++blk) {
        const size_t idx = (size_t)blk * NBUCK + b;
        const u32 c = counts[idx];
        counts[idx] = run;
        run += c;
    }
}

// A2: scatter entries of buckets [blo,bhi) to bucket-partitioned order.
// entry = (jlo6 << 25) | (k5 << 20) | r20.  LDS-local base bumps (no global atomics).
__global__ void __launch_bounds__(256) part_scatter(
    const int* __restrict__ om, const int* __restrict__ im,
    const u32* __restrict__ counts, const u32* __restrict__ totals,
    u32* __restrict__ entries, int blo, int bhi)
{
    __shared__ u32 base[NBUCK];                 // 62,500 B
    const u32* cb = counts + (size_t)blockIdx.x * NBUCK;
    for (int u = threadIdx.x; u < NBUCK; u += 256) base[u] = cb[u];
    __syncthreads();
    const u32 halfoff = totals[blo];            // totals[0] == 0 for half1
    const int lo = blockIdx.x * EPB, hi = lo + EPB;
    for (int e = lo + threadIdx.x * 4; e < hi; e += 1024) {
        const int4 j4 = *(const int4*)(om + e);
        const int4 r4 = *(const int4*)(im + e);
        const u32 k = (u32)(e / NPTS);          // e..e+3 share k (both %4==0)
        const int jj[4] = { j4.x, j4.y, j4.z, j4.w };
        const int rr[4] = { r4.x, r4.y, r4.z, r4.w };
#pragma unroll
        for (int u = 0; u < 4; ++u) {
            const int b = jj[u] >> 6;
            if (b >= blo && b < bhi) {
                const u32 p = atomicAdd(&base[b], 1u);
                entries[p - halfoff] =
                    ((u32)(jj[u] & 63) << 25) | (k << 20) | (u32)rr[u];
            }
        }
    }
}

// B: row-sort each bucket in place (LDS) and emit bins[j] (global CSR values).
__global__ void __launch_bounds__(256) rowsort(
    u32* __restrict__ entries, const u32* __restrict__ totals,
    u32* __restrict__ bins, int blo)
{
    __shared__ u32 ebuf[BCAP];
    __shared__ u32 rowst[SEG], rowpos[SEG];
    const int b = blo + blockIdx.x;
    const u32 halfoff = totals[blo];
    const u32 glo = totals[b];
    const u32 n0 = totals[b + 1] - glo;
    const u32 n = n0 < BCAP ? n0 : (u32)BCAP;
    const u32 lo = glo - halfoff;
    if (threadIdx.x < SEG) rowpos[threadIdx.x] = 0u;
    __syncthreads();
    for (u32 i = threadIdx.x; i < n; i += 256) {
        const u32 e = entries[lo + i];
        ebuf[i] = e;
        atomicAdd(&rowpos[(e >> 25) & 63], 1u);
    }
    __syncthreads();
    if (threadIdx.x == 0) {
        u32 run = 0;
        for (int t = 0; t < SEG; ++t) { const u32 c = rowpos[t]; rowst[t] = run; run += c; }
    }
    __syncthreads();
    if (threadIdx.x < SEG) {
        bins[b * SEG + threadIdx.x] = glo + rowst[threadIdx.x];
        rowpos[threadIdx.x] = rowst[threadIdx.x];
    }
    __syncthreads();
    for (u32 i = threadIdx.x; i < n; i += 256) {
        const u32 e = ebuf[i];
        const u32 p = atomicAdd(&rowpos[(e >> 25) & 63], 1u);
        entries[lo + p] = e & 0x1FFFFFFu;       // strip jlo -> (k<<20)|r
    }
}

// ================= gather / BN / final (unchanged numerics) =================

__global__ void __launch_bounds__(256) conv1_gather(
    const float* __restrict__ feats, const float* __restrict__ W1,
    const u32* __restrict__ entries, const u32* __restrict__ bins,
    int rlo, float* __restrict__ h1)
{
    __shared__ double w[KK * C];
    for (int u = threadIdx.x; u < KK * C; u += 256) w[u] = (double)W1[u];
    __syncthreads();
    const int g = threadIdx.x >> 4, c = threadIdx.x & 15;
    const int j = rlo + blockIdx.x * 16 + g;
    const u32 base = bins[rlo];
    u32 s = bins[j] - base;
    const u32 t = bins[j + 1] - base;
    double acc = 0.0;
    for (; s < t; ++s) {
        const u32 e = entries[s];
        const int r = (int)(e & 0xFFFFFu);
        const int k = (int)(e >> 20);
        acc += (double)feats[r] * w[k * C + c];
    }
    h1[(size_t)j * C + c] = (float)acc;
}

// conv2 gather v3: conflict-free LDS weight layout wt[k][q][c][4]
//   lane c, chunk q reads byte k*1024 + q*256 + c*16 -> bank interval (c*4)%32:
//   each 16-lane quarter-wave covers the 32 banks exactly twice = structural
//   minimum (2-way = free).  Plus a 2-stage pipeline prefetching next entry's
//   h1 row to overlap the random-gather latency.  Products and accumulation
//   order (c1 = 0..15) identical to before -> bit-identical output.
__global__ void __launch_bounds__(256) conv2_gather(
    const float* __restrict__ h1, const float* __restrict__ W2,
    const u32* __restrict__ entries, const u32* __restrict__ bins,
    int rlo, float* __restrict__ out2)
{
    __shared__ float wt[KK * 256];               // 27,648 B -> 5 blocks/CU
    for (int u = threadIdx.x; u < KK * 256; u += 256) {
        const int k = u >> 8, r = u & 255, c1 = r >> 4, c2 = r & 15;
        wt[k * 256 + (c1 >> 2) * 64 + c2 * 4 + (c1 & 3)] = W2[u];
    }
    __syncthreads();
    const int g = threadIdx.x >> 4, c = threadIdx.x & 15;
    const int j = rlo + blockIdx.x * 16 + g;
    const u32 base = bins[rlo];
    u32 s = bins[j] - base;
    const u32 t = bins[j + 1] - base;
    double acc = 0.0;
    const float* wbase = wt + c * 4;
    if (s < t) {
        u32 e = entries[s];
        {
            const float4* hp = (const float4*)(h1 + (size_t)(e & 0xFFFFFu) * C);
            float4 ha = hp[0], hb = hp[1], hc4 = hp[2], hd = hp[3];
            u32 k = e >> 20;
            for (;;) {
                const bool more = (s + 1u < t);
                float4 na, nb, nc4, nd; u32 nk = 0u;
                if (more) {
                    const u32 e2 = entries[s + 1u];
                    const float4* np = (const float4*)(h1 + (size_t)(e2 & 0xFFFFFu) * C);
                    na = np[0]; nb = np[1]; nc4 = np[2]; nd = np[3];
                    nk = e2 >> 20;
                }
                const float* wr = wbase + k * 256;
                const float4 wa = *(const float4*)(wr);
                const float4 wb = *(const float4*)(wr + 64);
                const float4 wc = *(const float4*)(wr + 128);
                const float4 wd = *(const float4*)(wr + 192);
                acc += (double)ha.x * (double)wa.x; acc += (double)ha.y * (double)wa.y;
                acc += (double)ha.z * (double)wa.z; acc += (double)ha.w * (double)wa.w;
                acc += (double)hb.x * (double)wb.x; acc += (double)hb.y * (double)wb.y;
                acc += (double)hb.z * (double)wb.z; acc += (double)hb.w * (double)wb.w;
                acc += (double)hc4.x * (double)wc.x; acc += (double)hc4.y * (double)wc.y;
                acc += (double)hc4.z * (double)wc.z; acc += (double)hc4.w * (double)wc.w;
                acc += (double)hd.x * (double)wd.x; acc += (double)hd.y * (double)wd.y;
                acc += (double)hd.z * (double)wd.z; acc += (double)hd.w * (double)wd.w;
                if (!more) break;
                ha = na; hb = nb; hc4 = nc4; hd = nd; k = nk;
                ++s;
            }
        }
    }
    out2[(size_t)j * C + c] = (float)acc;
}

__global__ void __launch_bounds__(256) bn_stats_f32(
    const float* __restrict__ x, double* __restrict__ stats)
{
    double s[C], s2[C];
#pragma unroll
    for (int c = 0; c < C; ++c) { s[c] = 0.0; s2[c] = 0.0; }
    const int stride = gridDim.x * 256;
    for (int i = blockIdx.x * 256 + threadIdx.x; i < NPTS; i += stride) {
        const float4* rp = (const float4*)(x + (size_t)i * C);
        float v[C];
#pragma unroll
        for (int q = 0; q < 4; ++q) {
            const float4 d = rp[q];
            v[4*q] = d.x; v[4*q+1] = d.y; v[4*q+2] = d.z; v[4*q+3] = d.w;
        }
#pragma unroll
        for (int c = 0; c < C; ++c) { const double dv = v[c]; s[c] += dv; s2[c] += dv * dv; }
    }
#pragma unroll
    for (int c = 0; c < C; ++c) {
#pragma unroll
        for (int off = 32; off > 0; off >>= 1) {
            s[c]  += __shfl_down(s[c],  off, 64);
            s2[c] += __shfl_down(s2[c], off, 64);
        }
    }
    if ((threadIdx.x & 63) == 0) {
#pragma unroll
        for (int c = 0; c < C; ++c) {
            atomAddF64(&stats[c], s[c]);
            atomAddF64(&stats[C + c], s2[c]);
        }
    }
}

__global__ void __launch_bounds__(256) bn_apply_f32(
    float* __restrict__ x, const double* __restrict__ stats,
    const float* __restrict__ gamma, const float* __restrict__ beta)
{
    __shared__ double sc[C], sh[C];
    if (threadIdx.x < C) {
        const int c = threadIdx.x;
        const double m = stats[c] / (double)NPTS;
        const double v = stats[C + c] / (double)NPTS - m * m;
        const double scale = (double)gamma[c] * rsqrt(v + 1e-5);
        sc[c] = scale;
        sh[c] = (double)beta[c] - m * scale;
    }
    __syncthreads();
    const size_t t = (size_t)blockIdx.x * 256 + threadIdx.x;
    if (t >= (size_t)NPTS * C) return;
    const int c = (int)(t & (C - 1));
    x[t] = (float)elu64((double)x[t] * sc[c] + sh[c]);
}

__global__ void __launch_bounds__(256) final_f32(
    const float* __restrict__ x, const double* __restrict__ stats,
    const float* __restrict__ gamma, const float* __restrict__ beta,
    const float* __restrict__ Wcls, const float* __restrict__ bcls,
    float* __restrict__ out)
{
    __shared__ double sc[C], sh[C], wc[C];
    __shared__ double bc;
    if (threadIdx.x < C) {
        const int c = threadIdx.x;
        const double m = stats[c] / (double)NPTS;
        const double v = stats[C + c] / (double)NPTS - m * m;
        const double scale = (double)gamma[c] * rsqrt(v + 1e-5);
        sc[c] = scale;
        sh[c] = (double)beta[c] - m * scale;
        wc[c] = (double)Wcls[c];
    }
    if (threadIdx.x == 0) bc = (double)bcls[0];
    __syncthreads();
    const int i = blockIdx.x * 256 + threadIdx.x;
    if (i >= NPTS) return;
    const float4* rp = (const float4*)(x + (size_t)i * C);
    float v[C];
#pragma unroll
    for (int q = 0; q < 4; ++q) {
        const float4 d = rp[q];
        v[4*q] = d.x; v[4*q+1] = d.y; v[4*q+2] = d.z; v[4*q+3] = d.w;
    }
    double hh[C];
    double cls = bc;
#pragma unroll
    for (int c = 0; c < C; ++c) {
        const double e = elu64((double)v[c] * sc[c] + sh[c]);
        hh[c] = e;
        cls += e * wc[c];
    }
    const bool keep = cls > 0.0;
    float* row = out + (size_t)i * 17;
#pragma unroll
    for (int c = 0; c < C; ++c) row[c] = keep ? (float)hh[c] : 0.f;
    row[16] = (float)cls;
}

// =====================================================================
// Memory plan (ws proven >= 128,000,256 B; d_out = 68,000,000 B scratch
// until final_f32 overwrites it):
//   ws + 0           : h1   [N,16] f32        64,000,000 B
//   ws + 64,000,000  : out2 [N,16] f32        64,000,000 B  (written only by gather2)
//   ws + 114,000,000 : counts u32[216*15625]  13,500,000 B  (dies before gather2-h2
//                      writes out2 rows >= R1, i.e. ws bytes >= 95,997,952)
//   ws + 127,500,000 : totals u32[15872]          63,488 B
//   ws + 127,563,488 : pt     u32[62]                248 B
//   ws + 128,000,000 : stats  f64[32]               256 B
//   d_out + 0          : entries u32 cap 14M   56,000,000 B (per half <=13.52M)
//   d_out + 56,000,000 : bins u32[N+1]          4,000,004 B
// Ordering guarantees: sort-h2 (reads counts) precedes gather2-h2 (clobbers it);
// gather-h1 reads bins[0..R1] (rowsort-h1 + make_bases seed bins[R1]).
// =====================================================================
extern "C" void kernel_launch(void* const* d_in, const int* in_sizes, int n_in,
                              void* d_out, int out_size, void* d_ws, size_t ws_size,
                              hipStream_t stream)
{
    const float* feats  = (const float*)d_in[0];
    const float* W1     = (const float*)d_in[1];
    const float* gamma1 = (const float*)d_in[2];
    const float* beta1  = (const float*)d_in[3];
    const float* W2     = (const float*)d_in[4];
    const float* gamma2 = (const float*)d_in[5];
    const float* beta2  = (const float*)d_in[6];
    const float* Wcls   = (const float*)d_in[7];
    const float* bcls   = (const float*)d_in[8];
    const int* in1 = (const int*)d_in[9];
    const int* om1 = (const int*)d_in[10];
    const int* in2 = (const int*)d_in[11];
    const int* om2 = (const int*)d_in[12];

    char* wsb = (char*)d_ws;
    float*  h1     = (float*)wsb;
    float*  out2   = (float*)(wsb + 64000000);
    u32*    counts = (u32*)(wsb + 114000000);
    u32*    totals = (u32*)(wsb + 127500000);
    u32*    pt     = (u32*)(wsb + 127563488);
    double* stats  = (double*)(wsb + 128000000);

    u32* entries = (u32*)d_out;
    u32* bins    = (u32*)((char*)d_out + 56000000);

    const int GA = (NPTS * C) / 256;        // 62,500
    const int G1 = R1 / 16;                 // 31,248 (half1 gather)
    const int G2 = (NPTS - R1) / 16;        // 31,252 (half2 gather)

    // ---------------- conv1: sort + gather ----------------
    part_hist<<<NBLKA, 256, 0, stream>>>(om1, counts);
    sum_cols<<<SBLK, 256, 0, stream>>>(counts, totals);
    scanT_k1<<<SBLK, 256, 0, stream>>>(totals, pt);
    scanT_k2<<<1, 64, 0, stream>>>(pt);
    scanT_k3<<<SBLK, 256, 0, stream>>>(totals, pt);
    make_bases<<<SBLK, 256, 0, stream>>>(counts, totals, bins);
    part_scatter<<<NBLKA, 256, 0, stream>>>(om1, in1, counts, totals, entries, 0, B1);
    rowsort<<<B1, 256, 0, stream>>>(entries, totals, bins, 0);
    conv1_gather<<<G1, 256, 0, stream>>>(feats, W1, entries, bins, 0, h1);
    part_scatter<<<NBLKA, 256, 0, stream>>>(om1, in1, counts, totals, entries, B1, NBUCK);
    rowsort<<<NBUCK - B1, 256, 0, stream>>>(entries, totals, bins, B1);
    conv1_gather<<<G2, 256, 0, stream>>>(feats, W1, entries, bins, R1, h1);

    hipMemsetAsync(stats, 0, 32 * sizeof(double), stream);
    bn_stats_f32<<<1024, 256, 0, stream>>>(h1, stats);
    bn_apply_f32<<<GA, 256, 0, stream>>>(h1, stats, gamma1, beta1);

    // ---------------- conv2: sort + gather ----------------
    part_hist<<<NBLKA, 256, 0, stream>>>(om2, counts);
    sum_cols<<<SBLK, 256, 0, stream>>>(counts, totals);
    scanT_k1<<<SBLK, 256, 0, stream>>>(totals, pt);
    scanT_k2<<<1, 64, 0, stream>>>(pt);
    scanT_k3<<<SBLK, 256, 0, stream>>>(totals, pt);
    make_bases<<<SBLK, 256, 0, stream>>>(counts, totals, bins);
    part_scatter<<<NBLKA, 256, 0, stream>>>(om2, in2, counts, totals, entries, 0, B1);
    rowsort<<<B1, 256, 0, stream>>>(entries, totals, bins, 0);
    conv2_gather<<<G1, 256, 0, stream>>>(h1, W2, entries, bins, 0, out2);
    part_scatter<<<NBLKA, 256, 0, stream>>>(om2, in2, counts, totals, entries, B1, NBUCK);
    rowsort<<<NBUCK - B1, 256, 0, stream>>>(entries, totals, bins, B1);
    conv2_gather<<<G2, 256, 0, stream>>>(h1, W2, entries, bins, R1, out2);

    hipMemsetAsync(stats, 0, 32 * sizeof(double), stream);
    bn_stats_f32<<<1024, 256, 0, stream>>>(out2, stats);
    final_f32<<<NBLK1, 256, 0, stream>>>(out2, stats, gamma2, beta2, Wcls, bcls, (float*)d_out);
}